// Round 7
// baseline (428.445 us; speedup 1.0000x reference)
//
#include <hip/hip_runtime.h>
#include <math.h>

// ---------------------------------------------------------------------------
// Sizes
// ---------------------------------------------------------------------------
#define NB   512
#define TT   60
#define FF   5
#define HH   128
#define G4   512
#define NN   2500
#define KK   50

#define O0 800
#define O1 1500
#define O2 2100

// ---------------------------------------------------------------------------
// Workspace layout (float offsets).
// B-fragment streams pre-swizzled into MFMA B-operand order (validated R6):
//   B-frag element: k = kb*32 + (l>>4)*8 + j ; n = g*128 + w*16 + (l&15)
// A-frag h layout (validated R6): addr = (k>>5)*512 + ((k>>3)&3)*128 + row*8 + (k&7)
// ---------------------------------------------------------------------------
#define OFF_B0F   0                        // L0 B-frags: 8w*5kb*4g*512h = 81920 halves
#define OFF_B1F   40960                    // L1 B-frags: 8w*8kb*4g*512h = 131072 halves
#define OFF_XA    106496                   // x A-frags: 32b*60t*512h = 983040 halves
#define OFF_BIAS0 598016                   // 512
#define OFF_BIAS1 598528                   // 512
#define OFF_A     599040                   // 2500
#define OFF_FS    601540                   // 512
#define OFF_H1    602052                   // 512*256

#define PREP_T0 81920
#define PREP_T1 212992
#define PREP_T2 1196032
#define PREP_T3 1196544
#define PREP_T4 1197056
#define PREP_TOTAL 1199556

typedef _Float16 f16x8 __attribute__((ext_vector_type(8)));
typedef float f32x4 __attribute__((ext_vector_type(4)));

__device__ __forceinline__ float sigf(float x) {
    return 1.0f / (1.0f + __expf(-x));
}
__device__ __forceinline__ float tanh2(float x) {
    float e = __expf(-2.0f * x);
    return fmaf(2.0f, 1.0f / (1.0f + e), -1.0f);
}

// ---------------------------------------------------------------------------
// K0: prep — B-frag swizzled fp16 weights, x A-frags, bias folds, a[n]
// ---------------------------------------------------------------------------
__global__ __launch_bounds__(256) void prep_kernel(
    const float* __restrict__ x,
    const float* __restrict__ W_ih0, const float* __restrict__ W_hh0,
    const float* __restrict__ b_ih0, const float* __restrict__ b_hh0,
    const float* __restrict__ W_ih1, const float* __restrict__ W_hh1,
    const float* __restrict__ b_ih1, const float* __restrict__ b_hh1,
    const float* __restrict__ conn_w, const float* __restrict__ sens,
    float* __restrict__ ws)
{
    int i = blockIdx.x * 256 + threadIdx.x;
    if (i >= PREP_TOTAL) return;

    if (i < PREP_T0) {                       // layer-0 B frags (K=160 padded)
        int j = i & 7, l = (i >> 3) & 63;
        int rest = i >> 9;
        int g = rest & 3;
        int kbw = rest >> 2;
        int kb = kbw % 5, w = kbw / 5;
        int k = kb * 32 + (l >> 4) * 8 + j;
        int n = g * 128 + w * 16 + (l & 15);
        float val = 0.f;
        if (k < 128)       val = W_hh0[n * HH + k];
        else if (k < 133)  val = W_ih0[n * FF + (k - 128)];
        ((_Float16*)(ws + OFF_B0F))[i] = (_Float16)val;
    } else if (i < PREP_T1) {                // layer-1 B frags (K=256: Wih1|Whh1)
        int v = i - PREP_T0;
        int j = v & 7, l = (v >> 3) & 63;
        int rest = v >> 9;
        int g = rest & 3;
        int kb = (rest >> 2) & 7;
        int w = rest >> 5;
        int k = kb * 32 + (l >> 4) * 8 + j;
        int n = g * 128 + w * 16 + (l & 15);
        float val = (k < 128) ? W_ih1[n * HH + k] : W_hh1[n * HH + (k - 128)];
        ((_Float16*)(ws + OFF_B1F))[v] = (_Float16)val;
    } else if (i < PREP_T2) {                // x A-frags
        int v = i - PREP_T1;
        int j = v & 7, l = (v >> 3) & 63;
        int rest = v >> 9;
        int t = rest % 60, bb = rest / 60;
        float val = 0.f;
        if (l < 16 && j < 5)
            val = x[(bb * 16 + (l & 15)) * (TT * FF) + t * FF + j];
        ((_Float16*)(ws + OFF_XA))[v] = (_Float16)val;
    } else if (i < PREP_T3) {
        int j = i - PREP_T2;
        ws[OFF_BIAS0 + j] = b_ih0[j] + b_hh0[j];
    } else if (i < PREP_T4) {
        int j = i - PREP_T3;
        ws[OFF_BIAS1 + j] = b_ih1[j] + b_hh1[j];
    } else {
        int n = i - PREP_T4;
        float s = 0.f;
        const float* cw = conn_w + n * KK;
        for (int k = 0; k < KK; ++k) s += cw[k];
        ws[OFF_A + n] = s * sens[n];
    }
}

// ---------------------------------------------------------------------------
// K1: MFMA 2-layer LSTM + feature head.
// 32 blocks x 512 threads (8 waves), block owns 16 batch rows (R6 skeleton).
// Changes vs R6:
//  - __launch_bounds__(512,2): 256-VGPR cap, B0's 20 frags held RESIDENT.
//  - B1 streamed with explicit 1-deep pipeline (load kb+1 while mfma kb).
//  - h double-buffered in LDS -> 2 barriers/step (was 4).
//  - XA prefetched one step ahead.
// ---------------------------------------------------------------------------
__global__ __launch_bounds__(512, 2) void lstm_mfma(
    const float* __restrict__ ws_ro,
    const float* __restrict__ fp_w1, const float* __restrict__ fp_b1,
    const float* __restrict__ fp_w2, const float* __restrict__ fp_b2,
    float* __restrict__ feat_sum)
{
    __shared__ __align__(16) _Float16 hcat[2 * 4096];   // dbuf, 16KB
    __shared__ float t1s[16][65];
    __shared__ float bss[16][33];

    const int tid = threadIdx.x;
    const int w = tid >> 6, l = tid & 63;
    const int u = w * 16 + (l & 15);
    const int row0 = (l >> 4) * 4;
    const int bb = blockIdx.x;

    // zero buffer 0 (4096 halves = 512 x 16B)
    ((uint4*)hcat)[tid] = make_uint4(0u, 0u, 0u, 0u);

    float bia0[4], bia1[4];
#pragma unroll
    for (int g = 0; g < 4; ++g) {
        bia0[g] = ws_ro[OFF_BIAS0 + g * 128 + u];
        bia1[g] = ws_ro[OFF_BIAS1 + g * 128 + u];
    }
    float c0[4] = {0.f, 0.f, 0.f, 0.f};
    float c1[4] = {0.f, 0.f, 0.f, 0.f};

    const f16x8* B0 = (const f16x8*)(ws_ro + OFF_B0F) + w * 20 * 64 + l;
    const f16x8* B1 = (const f16x8*)(ws_ro + OFF_B1F) + w * 32 * 64 + l;
    const f16x8* XA = (const f16x8*)(ws_ro + OFF_XA) + bb * 60 * 64 + l;
    const f16x8* HF = (const f16x8*)hcat;      // 512 frags per buffer

    // resident layer-0 weights: 20 frags = 80 VGPR
    f16x8 wb0[20];
#pragma unroll
    for (int i = 0; i < 20; ++i) wb0[i] = B0[i * 64];

    // h write base (halves within one buffer)
    const int h0base = (u >> 5) * 512 + ((u >> 3) & 3) * 128 + (u & 7);
    const int h1base = h0base + 2048;

    f16x8 xa = XA[0];

    __syncthreads();

    auto step = [&](int SRC, int DST, int t) {
        const f16x8* hs = HF + SRC * 512;
        const f16x8* hd = HF + DST * 512;
        _Float16* hw = hcat + DST * 4096;

        // prefetch next step's x frag
        f16x8 xan = XA[(t + 1 < TT ? t + 1 : TT - 1) * 64];

        // ---------- layer 0: gates = [h0|x] @ B0 (resident) ----------
        f32x4 a0 = {0.f,0.f,0.f,0.f}, a1 = {0.f,0.f,0.f,0.f};
        f32x4 a2 = {0.f,0.f,0.f,0.f}, a3 = {0.f,0.f,0.f,0.f};
#pragma unroll
        for (int kb = 0; kb < 4; ++kb) {
            f16x8 af = hs[kb * 64 + l];
            a0 = __builtin_amdgcn_mfma_f32_16x16x32_f16(af, wb0[kb*4+0], a0, 0,0,0);
            a1 = __builtin_amdgcn_mfma_f32_16x16x32_f16(af, wb0[kb*4+1], a1, 0,0,0);
            a2 = __builtin_amdgcn_mfma_f32_16x16x32_f16(af, wb0[kb*4+2], a2, 0,0,0);
            a3 = __builtin_amdgcn_mfma_f32_16x16x32_f16(af, wb0[kb*4+3], a3, 0,0,0);
        }
        a0 = __builtin_amdgcn_mfma_f32_16x16x32_f16(xa, wb0[16], a0, 0,0,0);
        a1 = __builtin_amdgcn_mfma_f32_16x16x32_f16(xa, wb0[17], a1, 0,0,0);
        a2 = __builtin_amdgcn_mfma_f32_16x16x32_f16(xa, wb0[18], a2, 0,0,0);
        a3 = __builtin_amdgcn_mfma_f32_16x16x32_f16(xa, wb0[19], a3, 0,0,0);

        // prefetch B1 kb0 while doing activation
        f16x8 q0 = B1[0*64], q1 = B1[1*64], q2 = B1[2*64], q3 = B1[3*64];

#pragma unroll
        for (int r = 0; r < 4; ++r) {
            float gi = sigf(a0[r] + bia0[0]);
            float gf = sigf(a1[r] + bia0[1]);
            float gg = tanh2(a2[r] + bia0[2]);
            float go = sigf(a3[r] + bia0[3]);
            c0[r] = gf * c0[r] + gi * gg;
            hw[h0base + (row0 + r) * 8] = (_Float16)(go * tanh2(c0[r]));
        }
        __syncthreads();                       // new h0 visible (writes were to DST)

        // ---------- layer 1: gates = [h0_new|h1_old] @ B1 (streamed) ----------
        f32x4 b0 = {0.f,0.f,0.f,0.f}, b1 = {0.f,0.f,0.f,0.f};
        f32x4 b2 = {0.f,0.f,0.f,0.f}, b3 = {0.f,0.f,0.f,0.f};
#pragma unroll
        for (int kb = 0; kb < 8; ++kb) {
            f16x8 af = (kb < 4) ? hd[kb * 64 + l] : hs[kb * 64 + l];
            f16x8 p0 = q0, p1 = q1, p2 = q2, p3 = q3;
            if (kb < 7) {
                q0 = B1[((kb+1)*4+0)*64]; q1 = B1[((kb+1)*4+1)*64];
                q2 = B1[((kb+1)*4+2)*64]; q3 = B1[((kb+1)*4+3)*64];
            }
            b0 = __builtin_amdgcn_mfma_f32_16x16x32_f16(af, p0, b0, 0,0,0);
            b1 = __builtin_amdgcn_mfma_f32_16x16x32_f16(af, p1, b1, 0,0,0);
            b2 = __builtin_amdgcn_mfma_f32_16x16x32_f16(af, p2, b2, 0,0,0);
            b3 = __builtin_amdgcn_mfma_f32_16x16x32_f16(af, p3, b3, 0,0,0);
        }
#pragma unroll
        for (int r = 0; r < 4; ++r) {
            float gi = sigf(b0[r] + bia1[0]);
            float gf = sigf(b1[r] + bia1[1]);
            float gg = tanh2(b2[r] + bia1[2]);
            float go = sigf(b3[r] + bia1[3]);
            c1[r] = gf * c1[r] + gi * gg;
            hw[h1base + (row0 + r) * 8] = (_Float16)(go * tanh2(c1[r]));
        }
        __syncthreads();                       // h1 visible; all SRC reads done
        xa = xan;
    };

    for (int t = 0; t < TT; t += 2) {
        step(0, 1, t);
        step(1, 0, t + 1);
    }
    // final h1 in buffer 0, halves [2048, 4096)

    // ---------- head MLP on hlast = h1 ----------
    for (int idx = tid; idx < 16 * 64; idx += 512) {
        int r = idx >> 6, m = idx & 63;
        float acc = fp_b1[m];
        const float* wp = fp_w1 + m * HH;
        for (int k = 0; k < HH; ++k) {
            float hv = (float)hcat[2048 + (k >> 5) * 512 +
                                   (r + ((k >> 3) & 3) * 16) * 8 + (k & 7)];
            acc = fmaf(wp[k], hv, acc);
        }
        t1s[r][m] = fmaxf(acc, 0.f);
    }
    __syncthreads();
    if (tid < 16 * 32) {
        int r = tid >> 5, q = tid & 31;
        float acc = fp_b2[q];
        const float* wp = fp_w2 + q * 64;
        for (int m = 0; m < 64; ++m) acc = fmaf(wp[m], t1s[r][m], acc);
        bss[r][q] = tanh2(acc);
    }
    __syncthreads();
    if (tid < 16) {
        float s = 0.f;
        for (int q = 0; q < 32; ++q) s += bss[tid][q];
        feat_sum[bb * 16 + tid] = s;
    }
}

// ---------------------------------------------------------------------------
// shared neuron activation
// ---------------------------------------------------------------------------
__device__ __forceinline__ float actn(int n, float pre, float th) {
    if (n < O0)       return sigf(pre - th);
    else if (n < O1)  return tanh2(pre);
    else if (n < O2)  return fmaxf(pre - th, 0.f);
    else              return sigf(pre);
}

// ---------------------------------------------------------------------------
// K2: h1 = relu(no @ int_w1.T + int_b1), activations recomputed on the fly.
// ---------------------------------------------------------------------------
__global__ __launch_bounds__(256) void gemm_h1(
    const float* __restrict__ feat_sum,
    const float* __restrict__ aw, const float* __restrict__ thr,
    const float* __restrict__ int_w1,   // 256 x 2500
    const float* __restrict__ int_b1,
    float* __restrict__ h1)
{
    __shared__ float As[32][33];
    __shared__ float Bs[32][33];
    const int b0 = blockIdx.x * 32;
    const int m0 = blockIdx.y * 32;
    const int tid = threadIdx.x;
    const int ty = tid >> 4, tx = tid & 15;
    const int li = tid >> 3;
    const int lj = (tid & 7) * 4;

    const float s_li = feat_sum[b0 + li];

    float acc00 = 0.f, acc01 = 0.f, acc10 = 0.f, acc11 = 0.f;

    for (int k0 = 0; k0 < NN; k0 += 32) {
        float4 av = make_float4(0.f, 0.f, 0.f, 0.f);
        if (k0 + lj < NN) {
            float4 aa = *(const float4*)(aw + k0 + lj);
            float4 tt = *(const float4*)(thr + k0 + lj);
            int n = k0 + lj;
            av.x = actn(n + 0, s_li * aa.x, tt.x);
            av.y = actn(n + 1, s_li * aa.y, tt.y);
            av.z = actn(n + 2, s_li * aa.z, tt.z);
            av.w = actn(n + 3, s_li * aa.w, tt.w);
        }
        As[li][lj + 0] = av.x; As[li][lj + 1] = av.y;
        As[li][lj + 2] = av.z; As[li][lj + 3] = av.w;

        float4 wv = make_float4(0.f, 0.f, 0.f, 0.f);
        if (k0 + lj < NN)
            wv = *(const float4*)(int_w1 + (m0 + li) * NN + k0 + lj);
        Bs[lj + 0][li] = wv.x; Bs[lj + 1][li] = wv.y;
        Bs[lj + 2][li] = wv.z; Bs[lj + 3][li] = wv.w;
        __syncthreads();

#pragma unroll 8
        for (int kk = 0; kk < 32; ++kk) {
            float a0 = As[ty * 2][kk],  a1 = As[ty * 2 + 1][kk];
            float w0 = Bs[kk][tx * 2],  w1 = Bs[kk][tx * 2 + 1];
            acc00 += a0 * w0; acc01 += a0 * w1;
            acc10 += a1 * w0; acc11 += a1 * w1;
        }
        __syncthreads();
    }
    const int bi = b0 + ty * 2, mj = m0 + tx * 2;
    h1[bi * 256 + mj]           = fmaxf(acc00 + int_b1[mj], 0.f);
    h1[bi * 256 + mj + 1]       = fmaxf(acc01 + int_b1[mj + 1], 0.f);
    h1[(bi + 1) * 256 + mj]     = fmaxf(acc10 + int_b1[mj], 0.f);
    h1[(bi + 1) * 256 + mj + 1] = fmaxf(acc11 + int_b1[mj + 1], 0.f);
}

// ---------------------------------------------------------------------------
// K3: tail MLP + group means + output assembly.  one wave per batch row.
// ---------------------------------------------------------------------------
__global__ __launch_bounds__(64) void tail_kernel(
    const float* __restrict__ h1,
    const float* __restrict__ feat_sum,
    const float* __restrict__ aw, const float* __restrict__ thr,
    const float* __restrict__ int_w2, const float* __restrict__ int_b2,
    const float* __restrict__ int_w3, const float* __restrict__ int_b3,
    const float* __restrict__ tw, const float* __restrict__ tb,
    const float* __restrict__ pw, const float* __restrict__ pb,
    const float* __restrict__ kw, const float* __restrict__ kb,
    const float* __restrict__ vw, const float* __restrict__ vb,
    const float* __restrict__ cw, const float* __restrict__ cb,
    float* __restrict__ out)
{
    const int b = blockIdx.x;
    const int lane = threadIdx.x;
    __shared__ float h2s[64];
    __shared__ float ints[32];
    __shared__ float outs[16];
    __shared__ float red[4][64];
    __shared__ float mred[4];

    // ---- group means (recomputed from feat_sum) ----
    {
        const float s = feat_sum[b];
        float m0 = 0.f, m1 = 0.f, m2 = 0.f, m3 = 0.f;
        for (int n = lane; n < NN; n += 64) {
            float v = actn(n, s * aw[n], thr[n]);
            if (n < O0) m0 += v; else if (n < O1) m1 += v;
            else if (n < O2) m2 += v; else m3 += v;
        }
        red[0][lane] = m0; red[1][lane] = m1;
        red[2][lane] = m2; red[3][lane] = m3;
    }

    // ---- h2 = relu(h1 @ int_w2.T + int_b2) ----
    {
        float acc = int_b2[lane];
        const float* hp = h1 + b * 256;
        const float* wp = int_w2 + lane * 256;
        for (int m = 0; m < 256; ++m) acc += wp[m] * hp[m];
        h2s[lane] = fmaxf(acc, 0.f);
    }
    __syncthreads();
    if (lane < 4) {
        float acc = 0.f;
        for (int i = 0; i < 64; ++i) acc += red[lane][i];
        const float inv[4] = {1.f/800.f, 1.f/700.f, 1.f/600.f, 1.f/400.f};
        mred[lane] = acc * inv[lane];
    }
    if (lane < 32) {
        float acc = int_b3[lane];
        const float* wp = int_w3 + lane * 64;
        for (int m = 0; m < 64; ++m) acc += wp[m] * h2s[m];
        ints[lane] = tanh2(acc);
    }
    __syncthreads();
    if (lane < 15) {
        const float* wsel; float bsel;
        if (lane < 3)       { wsel = tw + lane * 32;       bsel = tb[lane]; }
        else if (lane < 9)  { wsel = pw + (lane - 3) * 32; bsel = pb[lane - 3]; }
        else if (lane < 13) { wsel = kw + (lane - 9) * 32; bsel = kb[lane - 9]; }
        else if (lane == 13){ wsel = vw;                   bsel = vb[0]; }
        else                { wsel = cw;                   bsel = cb[0]; }
        float acc = bsel;
        for (int q = 0; q < 32; ++q) acc += wsel[q] * ints[q];
        outs[lane] = acc;
    }
    __syncthreads();
    if (lane < 20) {
        float v;
        if (lane < 15)       v = outs[lane];
        else if (lane == 15) v = sigf(outs[14]);
        else                 v = mred[lane - 16];
        out[b * 20 + lane] = v;
    }
}

// ---------------------------------------------------------------------------
extern "C" void kernel_launch(void* const* d_in, const int* in_sizes, int n_in,
                              void* d_out, int out_size, void* d_ws, size_t ws_size,
                              hipStream_t stream)
{
    const float* x      = (const float*)d_in[0];
    const float* W_ih0  = (const float*)d_in[1];
    const float* W_hh0  = (const float*)d_in[2];
    const float* b_ih0  = (const float*)d_in[3];
    const float* b_hh0  = (const float*)d_in[4];
    const float* W_ih1  = (const float*)d_in[5];
    const float* W_hh1  = (const float*)d_in[6];
    const float* b_ih1  = (const float*)d_in[7];
    const float* b_hh1  = (const float*)d_in[8];
    const float* fp_w1  = (const float*)d_in[9];
    const float* fp_b1  = (const float*)d_in[10];
    const float* fp_w2  = (const float*)d_in[11];
    const float* fp_b2  = (const float*)d_in[12];
    const float* conn_w = (const float*)d_in[13];
    const float* sens   = (const float*)d_in[14];
    const float* thr    = (const float*)d_in[15];
    const float* int_w1 = (const float*)d_in[16];
    const float* int_b1 = (const float*)d_in[17];
    const float* int_w2 = (const float*)d_in[18];
    const float* int_b2 = (const float*)d_in[19];
    const float* int_w3 = (const float*)d_in[20];
    const float* int_b3 = (const float*)d_in[21];
    const float* tw     = (const float*)d_in[22];
    const float* tb     = (const float*)d_in[23];
    const float* pw     = (const float*)d_in[24];
    const float* pb     = (const float*)d_in[25];
    const float* kw     = (const float*)d_in[26];
    const float* kb     = (const float*)d_in[27];
    const float* vw     = (const float*)d_in[28];
    const float* vb     = (const float*)d_in[29];
    const float* cw     = (const float*)d_in[30];
    const float* cb     = (const float*)d_in[31];
    // d_in[32] = conn_idx -- unused: acts is a feat_sum broadcast, so the
    // gather/einsum collapses to feat_sum[b] * rowsum(conn_w)[n].

    float* ws = (float*)d_ws;
    float* out = (float*)d_out;

    prep_kernel<<<(PREP_TOTAL + 255) / 256, 256, 0, stream>>>(
        x, W_ih0, W_hh0, b_ih0, b_hh0, W_ih1, W_hh1, b_ih1, b_hh1,
        conn_w, sens, ws);

    lstm_mfma<<<NB / 16, 512, 0, stream>>>(
        ws, fp_w1, fp_b1, fp_w2, fp_b2, ws + OFF_FS);

    {
        dim3 grid(NB / 32, 256 / 32);
        gemm_h1<<<grid, 256, 0, stream>>>(
            ws + OFF_FS, ws + OFF_A, thr, int_w1, int_b1, ws + OFF_H1);
    }

    tail_kernel<<<NB, 64, 0, stream>>>(
        ws + OFF_H1, ws + OFF_FS, ws + OFF_A, thr,
        int_w2, int_b2, int_w3, int_b3,
        tw, tb, pw, pb, kw, kb, vw, vb, cw, cb,
        out);
}